// Round 10
// baseline (304.231 us; speedup 1.0000x reference)
//
#include <hip/hip_runtime.h>
#include <stdint.h>

// Problem constants
#define NB       64
#define FIN      12
#define HD       64
#define NHEADS   4
#define DHEAD    16
#define NLAYERS  3
#define ODIM     128
#define LN_EPS   1e-5f
#define BTOT     8192

#define LDB      72    // u16 stride for fp16 LDS tiles (144 B rows, 16B-aligned)
#define NTH      256
#define NW       (NLAYERS * 4)
#define WFRAG    4096  // u16 per packed weight
#define WIN_U16  2048  // packed W_in^T (zero-padded K=32)
#define GUARD    (9 * LDB)   // 648 u16 = 1296 B zero guard (rows -9..-1 of Kh)

typedef unsigned int       u32;
typedef unsigned short     u16;
typedef unsigned long long u64;
typedef _Float16           f16;

typedef f16    f16x8 __attribute__((ext_vector_type(8)));
typedef f16    h2    __attribute__((ext_vector_type(2)));
typedef __fp16 hh2   __attribute__((ext_vector_type(2)));
typedef float  f32x4 __attribute__((ext_vector_type(4)));
union U128h { uint4 u; f16x8 v8; h2 v2[4]; };

#if __has_builtin(__builtin_amdgcn_exp2f)
  __device__ __forceinline__ float e2(float x) { return __builtin_amdgcn_exp2f(x); }
#else
  __device__ __forceinline__ float e2(float x) { return exp2f(x); }
#endif

__device__ __forceinline__ float fdot2h(h2 a, h2 b, float c) {
#if __has_builtin(__builtin_amdgcn_fdot2)
  return __builtin_amdgcn_fdot2(a, b, c, false);
#else
  return c + (float)a[0] * (float)b[0] + (float)a[1] * (float)b[1];
#endif
}

// pack two fp32 -> 2 fp16 in ONE inst (v_cvt_pkrtz_f16_f32); RTZ rounding,
// error <= 2^-10 rel vs 4x absmax margin.
#if __has_builtin(__builtin_amdgcn_cvt_pkrtz)
__device__ __forceinline__ u32 packh2(float a, float b) {
  hh2 p = __builtin_amdgcn_cvt_pkrtz(a, b);
  return *(u32*)&p;
}
#else
__device__ __forceinline__ u32 packh2(float a, float b) {
  h2 p = {(f16)a, (f16)b};
  return *(u32*)&p;
}
#endif
__device__ __forceinline__ void wb4(u16* __restrict__ dst, f32x4 a) {
  *(uint2*)dst = make_uint2(packh2(a[0], a[1]), packh2(a[2], a[3]));
}

struct __align__(16) Smem {
  u16 guard[GUARD];   // 1296  zeros: OOB k-reads for j<0 land here
  u16 Kh[NB * LDB];   // 9216  k fp16 (x-staging in phase 0; pool/y1 alias in head)
  u16 Vh[NB * LDB];   // 9216  v fp16 (j<0 v-reads hit Kh tail: finite, masked)
  u16 Qb[NB * LDB];   // 9216  q fp16; attention output o (j>63 overreads: finite)
};                    // 28944 B

// ---------------- prep: pack weights in B-fragment order, W_in^T (K zero-padded
// to 32), adjacency masks.
extern "C" __global__ void __launch_bounds__(256)
prep_pack(const float* __restrict__ Wq, const float* __restrict__ Wk,
          const float* __restrict__ Wv, const float* __restrict__ Wo,
          const float* __restrict__ W_in, const int* __restrict__ adj,
          u16* __restrict__ wsW) {
  const int w = blockIdx.x;
  if (w < NW) {
    const int l = w >> 2, ty = w & 3;
    const float* src = (ty == 0 ? Wq : ty == 1 ? Wk : ty == 2 ? Wv : Wo) + l * HD * HD;
    const float sc = (ty == 0) ? (0.25f * 1.44269504f) : 1.0f;
    u16* dst = wsW + w * WFRAG;
    for (int f = threadIdx.x; f < 512; f += 256) {
      const int lane = f & 63, kh = (f >> 6) & 1, nt = f >> 7;
      const int n  = nt * 16 + (lane & 15);
      const int k0 = kh * 32 + ((lane >> 4) & 3) * 8;
      u16 tmp[8];
      #pragma unroll
      for (int j = 0; j < 8; ++j) {
        f16 hv = (f16)(src[(k0 + j) * HD + n] * sc);
        tmp[j] = *(u16*)&hv;
      }
      *(uint4*)(dst + f * 8) = *(const uint4*)tmp;
    }
  } else if (w == NW) {
    const int t = threadIdx.x;
    const int mt = t >> 6, lane = t & 63;
    const int mm = lane & 15, qq = (lane >> 4) & 3;
    u16 tmp[8];
    #pragma unroll
    for (int j = 0; j < 8; ++j) {
      const int k = qq * 8 + j;
      f16 hv = (k < FIN) ? (f16)W_in[k * HD + mt * 16 + mm] : (f16)0.0f;
      tmp[j] = *(u16*)&hv;
    }
    *(uint4*)(wsW + NW * WFRAG + t * 8) = *(const uint4*)tmp;
  } else {
    const int t = threadIdx.x;
    u64* wsM = (u64*)(wsW + NW * WFRAG + WIN_U16);
    if (t < NB) {
      u64 mm = 0ull;
      for (int j = 0; j < NB; ++j)
        if (adj[t * NB + j] != 0) mm |= (1ull << j);
      wsM[t] = mm;
    }
  }
}

// Transposed GEMM: C^T = W^T @ H^T; A-frags = packed weights (global),
// B-frags in registers. C^T: feat = mt*16 + q*4 + r, node = wv*16 + (lane&15).
__device__ __forceinline__ void mmT(const u16* __restrict__ wf, U128h b0, U128h b1,
                                    int lane, f32x4 acc[4]) {
  #pragma unroll
  for (int mt = 0; mt < 4; ++mt) {
    U128h a0, a1;
    a0.u = *(const uint4*)(wf + ((mt * 2 + 0) * 64 + lane) * 8);
    a1.u = *(const uint4*)(wf + ((mt * 2 + 1) * 64 + lane) * 8);
    acc[mt] = __builtin_amdgcn_mfma_f32_16x16x32_f16(a0.v8, b0.v8, acc[mt], 0, 0, 0);
    acc[mt] = __builtin_amdgcn_mfma_f32_16x16x32_f16(a1.v8, b1.v8, acc[mt], 0, 0, 0);
  }
}

// Build h B-fragments from hr registers via cross-lane shuffle.
__device__ __forceinline__ void make_bfrags(const float hr[4][4], int q, int m,
                                            U128h& b0, U128h& b1) {
  u32 p[8];
  #pragma unroll
  for (int mt = 0; mt < 4; ++mt) {
    p[2 * mt]     = packh2(hr[mt][0], hr[mt][1]);
    p[2 * mt + 1] = packh2(hr[mt][2], hr[mt][3]);
  }
  const int sA = (2 * (q & 1)) * 16 + m;
  const int sB = sA + 16;
  u32 A[8], B[8];
  #pragma unroll
  for (int k = 0; k < 8; ++k) A[k] = (u32)__shfl((int)p[k], sA, 64);
  #pragma unroll
  for (int k = 0; k < 8; ++k) B[k] = (u32)__shfl((int)p[k], sB, 64);
  const bool hi = (q & 2) != 0;
  b0.u.x = hi ? A[2] : A[0];  b0.u.y = hi ? A[3] : A[1];
  b0.u.z = hi ? B[2] : B[0];  b0.u.w = hi ? B[3] : B[1];
  b1.u.x = hi ? A[6] : A[4];  b1.u.y = hi ? A[7] : A[5];
  b1.u.z = hi ? B[6] : B[4];  b1.u.w = hi ? B[7] : B[5];
}

extern "C" __global__ void __launch_bounds__(NTH, 4)
gnn_fused(const float* __restrict__ x, const float* __restrict__ b_in,
          const u16* __restrict__ wsW, const float* __restrict__ bo,
          const float* __restrict__ ln_g, const float* __restrict__ ln_b,
          const float* __restrict__ Wp1, const float* __restrict__ bp1,
          const float* __restrict__ Wp2, const float* __restrict__ bp2,
          float* __restrict__ out) {
  __shared__ Smem s;
  const int t    = threadIdx.x;
  const int lane = t & 63;
  const int wv   = t >> 6;
  const int eg   = (int)blockIdx.x;
  const int m    = lane & 15, q = lane >> 4;
  const int node = wv * 16 + m;

  const u16* wsWin = wsW + NW * WFRAG;
  const u64* wsM   = (const u64*)(wsWin + WIN_U16);

  // 8x8-grid stencil deltas (covers every edge incl. self); validity bits from
  // the adjacency mask, computed ONCE per thread.
  constexpr int DELTA[9] = {-9, -8, -7, -1, 0, 1, 7, 8, 9};
  u32 vb = 0;
  {
    const u64 mymask = wsM[lane];
    #pragma unroll
    for (int d = 0; d < 9; ++d) {
      const int j = lane + DELTA[d];
      const u32 ok = ((u32)j < 64u) ? (u32)((mymask >> j) & 1ull) : 0u;
      vb |= ok << d;
    }
  }

  // ---------------- phase 0: zero guard + x staging region, stage x as f16
  if (t < GUARD / 2) ((u32*)s.guard)[t] = 0u;       // 1296 B zeros, never rewritten
  ((uint4*)s.Kh)[t] = make_uint4(0u, 0u, 0u, 0u);   // 4096 B x-staging [node][32]
  __syncthreads();
  if (t < (NB * FIN) / 4) {
    const int nd = t / 3, pos = (t % 3) * 4;
    const float4 v4 = *(const float4*)(x + eg * NB * FIN + t * 4);
    *(uint2*)&s.Kh[nd * 32 + pos] = make_uint2(packh2(v4.x, v4.y), packh2(v4.z, v4.w));
  }
  __syncthreads();

  // ---------------- input projection via MFMA: h^T = W_in^T @ x^T (K=32 padded)
  float hr[4][4];   // hr[mt][r]: h[node][feat = mt*16 + q*4 + r]
  {
    U128h xb;
    xb.u = *(const uint4*)&s.Kh[node * 32 + q * 8];
    #pragma unroll
    for (int mt = 0; mt < 4; ++mt) {
      U128h a0;
      a0.u = *(const uint4*)(wsWin + (mt * 64 + lane) * 8);
      f32x4 acc = {0.f, 0.f, 0.f, 0.f};
      acc = __builtin_amdgcn_mfma_f32_16x16x32_f16(a0.v8, xb.v8, acc, 0, 0, 0);
      const f32x4 b4 = *(const f32x4*)&b_in[mt * 16 + q * 4];
      #pragma unroll
      for (int r = 0; r < 4; ++r) hr[mt][r] = acc[r] + b4[r];
    }
  }
  __syncthreads();   // x staging dead; Kh free for k

  // ---------------- transformer layers
  for (int l = 0; l < NLAYERS; ++l) {
    const u16* wl = wsW + (l * 4) * WFRAG;

    // h B-fragments from registers (shuffle transpose), then fused q/k/v
    {
      U128h b0, b1;
      make_bfrags(hr, q, m, b0, b1);

      f32x4 aq[4] = {{0,0,0,0},{0,0,0,0},{0,0,0,0},{0,0,0,0}};
      mmT(wl + 0 * WFRAG, b0, b1, lane, aq);
      #pragma unroll
      for (int mt = 0; mt < 4; ++mt)
        wb4(&s.Qb[node * LDB + mt * 16 + q * 4], aq[mt]);

      f32x4 ak[4] = {{0,0,0,0},{0,0,0,0},{0,0,0,0},{0,0,0,0}};
      mmT(wl + 1 * WFRAG, b0, b1, lane, ak);
      #pragma unroll
      for (int mt = 0; mt < 4; ++mt)
        wb4(&s.Kh[node * LDB + mt * 16 + q * 4], ak[mt]);

      f32x4 av[4] = {{0,0,0,0},{0,0,0,0},{0,0,0,0},{0,0,0,0}};
      mmT(wl + 2 * WFRAG, b0, b1, lane, av);
      #pragma unroll
      for (int mt = 0; mt < 4; ++mt)
        wb4(&s.Vh[node * LDB + mt * 16 + q * 4], av[mt]);
    }
    __syncthreads();

    // stencil attention: 9 uniform unrolled edges, all LDS offsets immediate.
    // Invalid edges read finite garbage / guard zeros; p masked to exact 0.
    {
      const int hh = wv, i = lane;
      const uint4* qp = (const uint4*)&s.Qb[i * LDB + hh * DHEAD];
      U128h q0, q1;
      q0.u = qp[0]; q1.u = qp[1];     // softmax scale*log2e pre-folded into Wq

      // row (i-9) frames: k-guard is s.guard; v-guard is Kh tail (finite, masked)
      const u16* kB = s.guard + i * LDB + hh * DHEAD;
      const u16* vB = s.Kh + (NB - 9 + i) * LDB + hh * DHEAD;

      float sum = 0.0f;
      h2 o2[8];
      #pragma unroll
      for (int c = 0; c < 8; ++c) o2[c] = (h2){(f16)0.0f, (f16)0.0f};

      #pragma unroll
      for (int d = 0; d < 9; ++d) {
        const int off = (DELTA[d] + 9) * LDB;   // compile-time immediate
        U128h k0, k1, v0, v1;
        k0.u = *(const uint4*)(kB + off);
        k1.u = *(const uint4*)(kB + off + 8);
        v0.u = *(const uint4*)(vB + off);
        v1.u = *(const uint4*)(vB + off + 8);
        float d0 = fdot2h(q0.v2[0], k0.v2[0], 0.0f);
        d0 = fdot2h(q0.v2[1], k0.v2[1], d0);
        d0 = fdot2h(q0.v2[2], k0.v2[2], d0);
        d0 = fdot2h(q0.v2[3], k0.v2[3], d0);
        float d1 = fdot2h(q1.v2[0], k1.v2[0], 0.0f);
        d1 = fdot2h(q1.v2[1], k1.v2[1], d1);
        d1 = fdot2h(q1.v2[2], k1.v2[2], d1);
        d1 = fdot2h(q1.v2[3], k1.v2[3], d1);
        const float pr = e2(d0 + d1);
        const float p  = ((vb >> d) & 1u) ? pr : 0.0f;   // exact 0 kills garbage
        sum += p;
        const f16 ph = (f16)p;
        const h2 p2 = {ph, ph};
        o2[0] += p2 * v0.v2[0]; o2[1] += p2 * v0.v2[1];
        o2[2] += p2 * v0.v2[2]; o2[3] += p2 * v0.v2[3];
        o2[4] += p2 * v1.v2[0]; o2[5] += p2 * v1.v2[1];
        o2[6] += p2 * v1.v2[2]; o2[7] += p2 * v1.v2[3];
      }

      const float rinv = 1.0f / sum;
      const f16 rh = (f16)rinv;
      const h2 r2 = {rh, rh};
      U128h w0, w1;
      #pragma unroll
      for (int c = 0; c < 4; ++c) w0.v2[c] = o2[c] * r2;
      #pragma unroll
      for (int c = 0; c < 4; ++c) w1.v2[c] = o2[c + 4] * r2;
      uint4* op = (uint4*)&s.Qb[i * LDB + hh * DHEAD];
      op[0] = w0.u; op[1] = w1.u;
    }
    __syncthreads();

    // u = h + o @ Wo + bo (transposed GEMM, o B-frags from LDS), LN over q-lanes
    {
      U128h b0, b1;
      const u16* obp = &s.Qb[node * LDB + q * 8];
      b0.u = *(const uint4*)obp;
      b1.u = *(const uint4*)(obp + 32);
      f32x4 ao[4] = {{0,0,0,0},{0,0,0,0},{0,0,0,0},{0,0,0,0}};
      mmT(wl + 3 * WFRAG, b0, b1, lane, ao);

      float uu[4][4];
      float s1 = 0.0f, s2 = 0.0f;
      #pragma unroll
      for (int mt = 0; mt < 4; ++mt) {
        const f32x4 bo4 = *(const f32x4*)&bo[l * HD + mt * 16 + q * 4];
        #pragma unroll
        for (int r = 0; r < 4; ++r) {
          const float v = hr[mt][r] + ao[mt][r] + bo4[r];
          uu[mt][r] = v;
          s1 += v;
          s2 += v * v;
        }
      }
      s1 += __shfl_xor(s1, 16, 64); s1 += __shfl_xor(s1, 32, 64);
      s2 += __shfl_xor(s2, 16, 64); s2 += __shfl_xor(s2, 32, 64);
      const float mu  = s1 * (1.0f / 64.0f);
      const float var = s2 * (1.0f / 64.0f) - mu * mu;
      const float rs  = rsqrtf(var + LN_EPS);
      #pragma unroll
      for (int mt = 0; mt < 4; ++mt) {
        const f32x4 g4 = *(const f32x4*)&ln_g[l * HD + mt * 16 + q * 4];
        const f32x4 b4 = *(const f32x4*)&ln_b[l * HD + mt * 16 + q * 4];
        #pragma unroll
        for (int r = 0; r < 4; ++r)
          hr[mt][r] = (uu[mt][r] - mu) * rs * g4[r] + b4[r];
      }
    }
    if (l + 1 < NLAYERS) __syncthreads();
  }

  // ---------------- head: butterfly over node-lanes, pool in Kh alias, MLP
  float* pool = (float*)s.Kh;   // Kh dead after last attention (barrier'd)
  float* y1   = pool + HD;
  __syncthreads();
  if (t < HD) pool[t] = 0.0f;
  __syncthreads();
  {
    #pragma unroll
    for (int mt = 0; mt < 4; ++mt)
      #pragma unroll
      for (int r = 0; r < 4; ++r) {
        float v = hr[mt][r];
        v += __shfl_xor(v, 1, 64); v += __shfl_xor(v, 2, 64);
        v += __shfl_xor(v, 4, 64); v += __shfl_xor(v, 8, 64);
        hr[mt][r] = v;
      }
    if (m == 0) {
      #pragma unroll
      for (int mt = 0; mt < 4; ++mt)
        #pragma unroll
        for (int r = 0; r < 4; ++r)
          atomicAdd(&pool[mt * 16 + q * 4 + r], hr[mt][r] * (1.0f / 64.0f));
    }
  }
  __syncthreads();
  if (t < HD) {
    float acc = bp1[t];
    #pragma unroll 8
    for (int k = 0; k < HD; ++k) acc = fmaf(pool[k], Wp1[k * HD + t], acc);
    y1[t] = fmaxf(acc, 0.0f);
  }
  __syncthreads();
  if (t < ODIM) {
    float acc = bp2[t];
    #pragma unroll 8
    for (int c = 0; c < HD; ++c) acc = fmaf(y1[c], Wp2[c * ODIM + t], acc);
    out[eg * ODIM + t] = acc;
  }
}

extern "C" void kernel_launch(void* const* d_in, const int* in_sizes, int n_in,
                              void* d_out, int out_size, void* d_ws, size_t ws_size,
                              hipStream_t stream) {
  const float* x    = (const float*)d_in[0];
  const int*   adj  = (const int*)d_in[1];
  const float* W_in = (const float*)d_in[2];
  const float* b_in = (const float*)d_in[3];
  const float* Wq   = (const float*)d_in[4];
  const float* Wk   = (const float*)d_in[5];
  const float* Wv   = (const float*)d_in[6];
  const float* Wo   = (const float*)d_in[7];
  const float* bo   = (const float*)d_in[8];
  const float* lng  = (const float*)d_in[9];
  const float* lnb  = (const float*)d_in[10];
  const float* Wp1  = (const float*)d_in[11];
  const float* bp1  = (const float*)d_in[12];
  const float* Wp2  = (const float*)d_in[13];
  const float* bp2  = (const float*)d_in[14];
  float* outp = (float*)d_out;
  u16*   wsW  = (u16*)d_ws;   // 12*4096 + 2048 u16 + 512 B masks = ~103 KB

  hipLaunchKernelGGL(prep_pack, dim3(NW + 2), dim3(256), 0, stream,
                     Wq, Wk, Wv, Wo, W_in, adj, wsW);
  hipLaunchKernelGGL(gnn_fused, dim3(BTOT), dim3(NTH), 0, stream,
                     x, b_in, wsW, bo, lng, lnb, Wp1, bp1, Wp2, bp2, outp);
}

// Round 11
// 284.681 us; speedup vs baseline: 1.0687x; 1.0687x over previous
//
#include <hip/hip_runtime.h>
#include <stdint.h>

// Problem constants
#define NB       64
#define FIN      12
#define HD       64
#define NHEADS   4
#define DHEAD    16
#define NLAYERS  3
#define ODIM     128
#define LN_EPS   1e-5f
#define BTOT     8192

#define LDB      72    // u16 stride for fp16 LDS tiles (144 B rows, 16B-aligned)
#define NTH      256
#define NW       (NLAYERS * 4)
#define WFRAG    4096  // u16 per packed weight
#define WIN_U16  2048  // packed W_in^T (zero-padded K=32)

typedef unsigned int       u32;
typedef unsigned short     u16;
typedef unsigned long long u64;
typedef _Float16           f16;

typedef f16    f16x8 __attribute__((ext_vector_type(8)));
typedef f16    h2    __attribute__((ext_vector_type(2)));
typedef __fp16 hh2   __attribute__((ext_vector_type(2)));
typedef float  f32x4 __attribute__((ext_vector_type(4)));
union U128h { uint4 u; f16x8 v8; h2 v2[4]; };

#if __has_builtin(__builtin_amdgcn_exp2f)
  __device__ __forceinline__ float e2(float x) { return __builtin_amdgcn_exp2f(x); }
#else
  __device__ __forceinline__ float e2(float x) { return exp2f(x); }
#endif

__device__ __forceinline__ float fdot2h(h2 a, h2 b, float c) {
#if __has_builtin(__builtin_amdgcn_fdot2)
  return __builtin_amdgcn_fdot2(a, b, c, false);
#else
  return c + (float)a[0] * (float)b[0] + (float)a[1] * (float)b[1];
#endif
}

// pack two fp32 -> 2 fp16 in ONE inst (v_cvt_pkrtz_f16_f32). RTZ; verified
// absmax-neutral in round 10 (bit-identical 4.8828e-4).
#if __has_builtin(__builtin_amdgcn_cvt_pkrtz)
__device__ __forceinline__ u32 packh2(float a, float b) {
  hh2 p = __builtin_amdgcn_cvt_pkrtz(a, b);
  return *(u32*)&p;
}
#else
__device__ __forceinline__ u32 packh2(float a, float b) {
  h2 p = {(f16)a, (f16)b};
  return *(u32*)&p;
}
#endif
__device__ __forceinline__ void wb4(u16* __restrict__ dst, f32x4 a) {
  *(uint2*)dst = make_uint2(packh2(a[0], a[1]), packh2(a[2], a[3]));
}

struct __align__(16) Smem {
  u16 Kh[NB * LDB];   // 9216  k fp16 (x-staging [node][32] f16 in phase 0; pool/y1 in head)
  u16 Vh[NB * LDB];   // 9216  v fp16
  u16 Qb[NB * LDB];   // 9216  q fp16; attention output o
};                    // 27648 B. Occupancy is VGPR-class-bound: 5 blocks/CU needs
                      // <=64 VGPR (m69 step) -> spills (r8/r10). 4 blocks/CU, no spill.

// ---------------- prep: pack weights in B-fragment order, W_in^T (K zero-padded
// to 32), adjacency masks.
extern "C" __global__ void __launch_bounds__(256)
prep_pack(const float* __restrict__ Wq, const float* __restrict__ Wk,
          const float* __restrict__ Wv, const float* __restrict__ Wo,
          const float* __restrict__ W_in, const int* __restrict__ adj,
          u16* __restrict__ wsW) {
  const int w = blockIdx.x;
  if (w < NW) {
    const int l = w >> 2, ty = w & 3;
    const float* src = (ty == 0 ? Wq : ty == 1 ? Wk : ty == 2 ? Wv : Wo) + l * HD * HD;
    const float sc = (ty == 0) ? (0.25f * 1.44269504f) : 1.0f;
    u16* dst = wsW + w * WFRAG;
    for (int f = threadIdx.x; f < 512; f += 256) {
      const int lane = f & 63, kh = (f >> 6) & 1, nt = f >> 7;
      const int n  = nt * 16 + (lane & 15);
      const int k0 = kh * 32 + ((lane >> 4) & 3) * 8;
      u16 tmp[8];
      #pragma unroll
      for (int j = 0; j < 8; ++j) {
        f16 hv = (f16)(src[(k0 + j) * HD + n] * sc);
        tmp[j] = *(u16*)&hv;
      }
      *(uint4*)(dst + f * 8) = *(const uint4*)tmp;
    }
  } else if (w == NW) {
    const int t = threadIdx.x;
    const int mt = t >> 6, lane = t & 63;
    const int mm = lane & 15, qq = (lane >> 4) & 3;
    u16 tmp[8];
    #pragma unroll
    for (int j = 0; j < 8; ++j) {
      const int k = qq * 8 + j;
      f16 hv = (k < FIN) ? (f16)W_in[k * HD + mt * 16 + mm] : (f16)0.0f;
      tmp[j] = *(u16*)&hv;
    }
    *(uint4*)(wsW + NW * WFRAG + t * 8) = *(const uint4*)tmp;
  } else {
    const int t = threadIdx.x;
    u64* wsM = (u64*)(wsW + NW * WFRAG + WIN_U16);
    if (t < NB) {
      u64 mm = 0ull;
      for (int j = 0; j < NB; ++j)
        if (adj[t * NB + j] != 0) mm |= (1ull << j);
      wsM[t] = mm;
    }
  }
}

// Transposed GEMM: C^T = W^T @ H^T; A-frags = packed weights (global),
// B-frags in registers. C^T: feat = mt*16 + q*4 + r, node = wv*16 + (lane&15).
__device__ __forceinline__ void mmT(const u16* __restrict__ wf, U128h b0, U128h b1,
                                    int lane, f32x4 acc[4]) {
  #pragma unroll
  for (int mt = 0; mt < 4; ++mt) {
    U128h a0, a1;
    a0.u = *(const uint4*)(wf + ((mt * 2 + 0) * 64 + lane) * 8);
    a1.u = *(const uint4*)(wf + ((mt * 2 + 1) * 64 + lane) * 8);
    acc[mt] = __builtin_amdgcn_mfma_f32_16x16x32_f16(a0.v8, b0.v8, acc[mt], 0, 0, 0);
    acc[mt] = __builtin_amdgcn_mfma_f32_16x16x32_f16(a1.v8, b1.v8, acc[mt], 0, 0, 0);
  }
}

// Build h B-fragments from hr registers via cross-lane shuffle (no LDS round-trip).
// Dest lane (q,m) pulls packed h2 words from lanes sA = 2(q&1)*16+m, sB = sA+16;
// slot set selected by q>>1.
__device__ __forceinline__ void make_bfrags(const float hr[4][4], int q, int m,
                                            U128h& b0, U128h& b1) {
  u32 p[8];
  #pragma unroll
  for (int mt = 0; mt < 4; ++mt) {
    p[2 * mt]     = packh2(hr[mt][0], hr[mt][1]);
    p[2 * mt + 1] = packh2(hr[mt][2], hr[mt][3]);
  }
  const int sA = (2 * (q & 1)) * 16 + m;
  const int sB = sA + 16;
  u32 A[8], B[8];
  #pragma unroll
  for (int k = 0; k < 8; ++k) A[k] = (u32)__shfl((int)p[k], sA, 64);
  #pragma unroll
  for (int k = 0; k < 8; ++k) B[k] = (u32)__shfl((int)p[k], sB, 64);
  const bool hi = (q & 2) != 0;   // q>>1
  b0.u.x = hi ? A[2] : A[0];  b0.u.y = hi ? A[3] : A[1];
  b0.u.z = hi ? B[2] : B[0];  b0.u.w = hi ? B[3] : B[1];
  b1.u.x = hi ? A[6] : A[4];  b1.u.y = hi ? A[7] : A[5];
  b1.u.z = hi ? B[6] : B[4];  b1.u.w = hi ? B[7] : B[5];
}

// one attention edge: s = q.k (fdot2 chains), p = exp2(s), o += p*v (pk_fma_f16)
__device__ __forceinline__ void attn_edge(const U128h& q0, const U128h& q1,
                                          U128h k0, U128h k1, U128h v0, U128h v1,
                                          float& sum, h2* __restrict__ o) {
  float d0 = fdot2h(q0.v2[0], k0.v2[0], 0.0f);
  d0 = fdot2h(q0.v2[1], k0.v2[1], d0);
  d0 = fdot2h(q0.v2[2], k0.v2[2], d0);
  d0 = fdot2h(q0.v2[3], k0.v2[3], d0);
  float d1 = fdot2h(q1.v2[0], k1.v2[0], 0.0f);
  d1 = fdot2h(q1.v2[1], k1.v2[1], d1);
  d1 = fdot2h(q1.v2[2], k1.v2[2], d1);
  d1 = fdot2h(q1.v2[3], k1.v2[3], d1);
  const float p = e2(d0 + d1);
  sum += p;
  const f16 ph = (f16)p;
  const h2 p2 = {ph, ph};
  o[0] += p2 * v0.v2[0]; o[1] += p2 * v0.v2[1];
  o[2] += p2 * v0.v2[2]; o[3] += p2 * v0.v2[3];
  o[4] += p2 * v1.v2[0]; o[5] += p2 * v1.v2[1];
  o[6] += p2 * v1.v2[2]; o[7] += p2 * v1.v2[3];
}

extern "C" __global__ void __launch_bounds__(NTH, 4)
gnn_fused(const float* __restrict__ x, const float* __restrict__ b_in,
          const u16* __restrict__ wsW, const float* __restrict__ bo,
          const float* __restrict__ ln_g, const float* __restrict__ ln_b,
          const float* __restrict__ Wp1, const float* __restrict__ bp1,
          const float* __restrict__ Wp2, const float* __restrict__ bp2,
          float* __restrict__ out) {
  __shared__ Smem s;
  const int t    = threadIdx.x;
  const int lane = t & 63;
  const int wv   = t >> 6;
  const int eg   = (int)blockIdx.x;
  const int m    = lane & 15, q = lane >> 4;
  const int node = wv * 16 + m;

  const u16* wsWin = wsW + NW * WFRAG;
  const u64* wsM   = (const u64*)(wsWin + WIN_U16);

  // per-thread adjacency mask (attention uses i = lane); no LDS copy
  const u64 mymask = wsM[lane];

  // ---------------- phase 0: zero + stage x as f16 [node][32] in Kh region
  ((uint4*)s.Kh)[t] = make_uint4(0u, 0u, 0u, 0u);   // 4096 B = staging region
  __syncthreads();
  if (t < (NB * FIN) / 4) {
    const int nd = t / 3, pos = (t % 3) * 4;
    const float4 v4 = *(const float4*)(x + eg * NB * FIN + t * 4);
    *(uint2*)&s.Kh[nd * 32 + pos] = make_uint2(packh2(v4.x, v4.y), packh2(v4.z, v4.w));
  }
  __syncthreads();

  // ---------------- input projection via MFMA: h^T = W_in^T @ x^T (K=32 padded)
  float hr[4][4];   // hr[mt][r]: h[node][feat = mt*16 + q*4 + r]
  {
    U128h xb;
    xb.u = *(const uint4*)&s.Kh[node * 32 + q * 8];
    #pragma unroll
    for (int mt = 0; mt < 4; ++mt) {
      U128h a0;
      a0.u = *(const uint4*)(wsWin + (mt * 64 + lane) * 8);
      f32x4 acc = {0.f, 0.f, 0.f, 0.f};
      acc = __builtin_amdgcn_mfma_f32_16x16x32_f16(a0.v8, xb.v8, acc, 0, 0, 0);
      const f32x4 b4 = *(const f32x4*)&b_in[mt * 16 + q * 4];
      #pragma unroll
      for (int r = 0; r < 4; ++r) hr[mt][r] = acc[r] + b4[r];
    }
  }
  __syncthreads();   // x staging dead; Kh free for k

  // ---------------- transformer layers
  for (int l = 0; l < NLAYERS; ++l) {
    const u16* wl = wsW + (l * 4) * WFRAG;

    // h B-fragments from registers (shuffle transpose), then fused q/k/v
    {
      U128h b0, b1;
      make_bfrags(hr, q, m, b0, b1);

      f32x4 aq[4] = {{0,0,0,0},{0,0,0,0},{0,0,0,0},{0,0,0,0}};
      mmT(wl + 0 * WFRAG, b0, b1, lane, aq);
      #pragma unroll
      for (int mt = 0; mt < 4; ++mt)
        wb4(&s.Qb[node * LDB + mt * 16 + q * 4], aq[mt]);

      f32x4 ak[4] = {{0,0,0,0},{0,0,0,0},{0,0,0,0},{0,0,0,0}};
      mmT(wl + 1 * WFRAG, b0, b1, lane, ak);
      #pragma unroll
      for (int mt = 0; mt < 4; ++mt)
        wb4(&s.Kh[node * LDB + mt * 16 + q * 4], ak[mt]);

      f32x4 av[4] = {{0,0,0,0},{0,0,0,0},{0,0,0,0},{0,0,0,0}};
      mmT(wl + 2 * WFRAG, b0, b1, lane, av);
      #pragma unroll
      for (int mt = 0; mt < 4; ++mt)
        wb4(&s.Vh[node * LDB + mt * 16 + q * 4], av[mt]);
    }
    __syncthreads();

    // sparse masked attention (wave = head, lane = node), ping-pong k/v prefetch
    {
      const int hh = wv, i = lane;
      const uint4* qp = (const uint4*)&s.Qb[i * LDB + hh * DHEAD];
      U128h q0, q1;
      q0.u = qp[0]; q1.u = qp[1];     // softmax scale*log2e pre-folded into Wq

      u64 mk = mymask;
      float sum = 0.0f;
      h2 o2[8];
      #pragma unroll
      for (int c = 0; c < 8; ++c) o2[c] = (h2){(f16)0.0f, (f16)0.0f};

      int j = (int)__builtin_ctzll(mk); mk &= mk - 1;
      const uint4* kp = (const uint4*)&s.Kh[j * LDB + hh * DHEAD];
      const uint4* vp = (const uint4*)&s.Vh[j * LDB + hh * DHEAD];
      U128h k0, k1, v0, v1;
      k0.u = kp[0]; k1.u = kp[1]; v0.u = vp[0]; v1.u = vp[1];

      for (;;) {
        if (!mk) { attn_edge(q0, q1, k0, k1, v0, v1, sum, o2); break; }
        j = (int)__builtin_ctzll(mk); mk &= mk - 1;
        const uint4* kp2 = (const uint4*)&s.Kh[j * LDB + hh * DHEAD];
        const uint4* vp2 = (const uint4*)&s.Vh[j * LDB + hh * DHEAD];
        U128h k0b, k1b, v0b, v1b;
        k0b.u = kp2[0]; k1b.u = kp2[1]; v0b.u = vp2[0]; v1b.u = vp2[1];
        attn_edge(q0, q1, k0, k1, v0, v1, sum, o2);
        if (!mk) { attn_edge(q0, q1, k0b, k1b, v0b, v1b, sum, o2); break; }
        j = (int)__builtin_ctzll(mk); mk &= mk - 1;
        kp = (const uint4*)&s.Kh[j * LDB + hh * DHEAD];
        vp = (const uint4*)&s.Vh[j * LDB + hh * DHEAD];
        k0.u = kp[0]; k1.u = kp[1]; v0.u = vp[0]; v1.u = vp[1];
        attn_edge(q0, q1, k0b, k1b, v0b, v1b, sum, o2);
      }

      const float rinv = 1.0f / sum;
      const f16 rh = (f16)rinv;
      const h2 r2 = {rh, rh};
      U128h w0, w1;
      #pragma unroll
      for (int c = 0; c < 4; ++c) w0.v2[c] = o2[c] * r2;
      #pragma unroll
      for (int c = 0; c < 4; ++c) w1.v2[c] = o2[c + 4] * r2;
      uint4* op = (uint4*)&s.Qb[i * LDB + hh * DHEAD];
      op[0] = w0.u; op[1] = w1.u;
    }
    __syncthreads();

    // u = h + o @ Wo + bo (transposed GEMM, o B-frags from LDS), LN over q-lanes
    {
      U128h b0, b1;
      const u16* obp = &s.Qb[node * LDB + q * 8];
      b0.u = *(const uint4*)obp;
      b1.u = *(const uint4*)(obp + 32);
      f32x4 ao[4] = {{0,0,0,0},{0,0,0,0},{0,0,0,0},{0,0,0,0}};
      mmT(wl + 3 * WFRAG, b0, b1, lane, ao);

      float uu[4][4];
      float s1 = 0.0f, s2 = 0.0f;
      #pragma unroll
      for (int mt = 0; mt < 4; ++mt) {
        const f32x4 bo4 = *(const f32x4*)&bo[l * HD + mt * 16 + q * 4];
        #pragma unroll
        for (int r = 0; r < 4; ++r) {
          const float v = hr[mt][r] + ao[mt][r] + bo4[r];
          uu[mt][r] = v;
          s1 += v;
          s2 += v * v;
        }
      }
      s1 += __shfl_xor(s1, 16, 64); s1 += __shfl_xor(s1, 32, 64);
      s2 += __shfl_xor(s2, 16, 64); s2 += __shfl_xor(s2, 32, 64);
      const float mu  = s1 * (1.0f / 64.0f);
      const float var = s2 * (1.0f / 64.0f) - mu * mu;
      const float rs  = rsqrtf(var + LN_EPS);
      #pragma unroll
      for (int mt = 0; mt < 4; ++mt) {
        const f32x4 g4 = *(const f32x4*)&ln_g[l * HD + mt * 16 + q * 4];
        const f32x4 b4 = *(const f32x4*)&ln_b[l * HD + mt * 16 + q * 4];
        #pragma unroll
        for (int r = 0; r < 4; ++r)
          hr[mt][r] = (uu[mt][r] - mu) * rs * g4[r] + b4[r];
      }
    }
    if (l + 1 < NLAYERS) __syncthreads();   // protect Qb reads before next qkv writes
  }

  // ---------------- head: butterfly over node-lanes, pool in Kh alias, MLP
  float* pool = (float*)s.Kh;   // Kh dead (last read: layer-2 attention, barrier'd)
  float* y1   = pool + HD;
  __syncthreads();              // all waves past layer-2 Qb reads & Kh reads
  if (t < HD) pool[t] = 0.0f;
  __syncthreads();
  {
    #pragma unroll
    for (int mt = 0; mt < 4; ++mt)
      #pragma unroll
      for (int r = 0; r < 4; ++r) {
        float v = hr[mt][r];
        v += __shfl_xor(v, 1, 64); v += __shfl_xor(v, 2, 64);
        v += __shfl_xor(v, 4, 64); v += __shfl_xor(v, 8, 64);
        hr[mt][r] = v;
      }
    if (m == 0) {
      #pragma unroll
      for (int mt = 0; mt < 4; ++mt)
        #pragma unroll
        for (int r = 0; r < 4; ++r)
          atomicAdd(&pool[mt * 16 + q * 4 + r], hr[mt][r] * (1.0f / 64.0f));
    }
  }
  __syncthreads();
  if (t < HD) {
    float acc = bp1[t];
    #pragma unroll 8
    for (int k = 0; k < HD; ++k) acc = fmaf(pool[k], Wp1[k * HD + t], acc);
    y1[t] = fmaxf(acc, 0.0f);
  }
  __syncthreads();
  if (t < ODIM) {
    float acc = bp2[t];
    #pragma unroll 8
    for (int c = 0; c < HD; ++c) acc = fmaf(y1[c], Wp2[c * ODIM + t], acc);
    out[eg * ODIM + t] = acc;
  }
}

extern "C" void kernel_launch(void* const* d_in, const int* in_sizes, int n_in,
                              void* d_out, int out_size, void* d_ws, size_t ws_size,
                              hipStream_t stream) {
  const float* x    = (const float*)d_in[0];
  const int*   adj  = (const int*)d_in[1];
  const float* W_in = (const float*)d_in[2];
  const float* b_in = (const float*)d_in[3];
  const float* Wq   = (const float*)d_in[4];
  const float* Wk   = (const float*)d_in[5];
  const float* Wv   = (const float*)d_in[6];
  const float* Wo   = (const float*)d_in[7];
  const float* bo   = (const float*)d_in[8];
  const float* lng  = (const float*)d_in[9];
  const float* lnb  = (const float*)d_in[10];
  const float* Wp1  = (const float*)d_in[11];
  const float* bp1  = (const float*)d_in[12];
  const float* Wp2  = (const float*)d_in[13];
  const float* bp2  = (const float*)d_in[14];
  float* outp = (float*)d_out;
  u16*   wsW  = (u16*)d_ws;   // 12*4096 + 2048 u16 + 512 B masks = ~103 KB

  hipLaunchKernelGGL(prep_pack, dim3(NW + 2), dim3(256), 0, stream,
                     Wq, Wk, Wv, Wo, W_in, adj, wsW);
  hipLaunchKernelGGL(gnn_fused, dim3(BTOT), dim3(NTH), 0, stream,
                     x, b_in, wsW, bo, lng, lnb, Wp1, bp1, Wp2, bp2, outp);
}